// Round 23
// baseline (355.589 us; speedup 1.0000x reference)
//
#include <hip/hip_runtime.h>
#include <hip/hip_bf16.h>

#define NTOT  1048576
#define MWG   128          // rows per workgroup
#define BLK   512          // 8 waves in 2x4: wave (wm,wn) owns rows [wm*64,+64) x ntiles [wn*2,+2)
#define ROWB  384          // act row stride bytes; XOR swizzle (m&7)<<4, bases precomputed
#define ACT_BYTES  (MWG * ROWB)          // 49152; 2 blocks/CU = 16 waves = 4/SIMD

typedef __attribute__((ext_vector_type(8))) short  bf16x8;
typedef __attribute__((ext_vector_type(4))) float  f32x4;

// lgkm-only barrier: LDS ordering needs lgkmcnt only; no vmcnt drain -> global loads
// issued before the barrier stay in flight across it (weight prefetch relies on this)
__device__ __forceinline__ void barL() {
  asm volatile("s_waitcnt lgkmcnt(0)\n\ts_barrier" ::: "memory");
}

__device__ __forceinline__ unsigned short f2bf(float f) {
  unsigned u = __float_as_uint(f);
  u += 0x7fffu + ((u >> 16) & 1u);          // RNE
  return (unsigned short)(u >> 16);
}

__device__ __forceinline__ unsigned pk2bf(float lo, float hi) {
  float2 t; t.x = lo; t.y = hi;
  __hip_bfloat162 b = __float22bfloat162_rn(t);   // RNE
  return *(unsigned*)&b;
}

// ---------------- weight prepack (identical to R6..R22) ----------------
__global__ __launch_bounds__(256) void prepack_k(
    const float* __restrict__ s0, const float* __restrict__ s1,
    const float* __restrict__ s2, const float* __restrict__ s3,
    const float* __restrict__ s4, const float* __restrict__ s5,
    const float* __restrict__ s6, const float* __restrict__ s7,
    const float* __restrict__ s8, const float* __restrict__ s9,
    const float* __restrict__ s10, unsigned short* __restrict__ dst)
{
  const int nw_[11]  = {128,128,128,128,128,128,128,128,144, 64, 16};
  const int kw_[11]  = { 64,128,128,128,128,192,128,128,128,192, 64};
  const int nc_[11]  = {128,128,128,128,128,128,128,128,129, 64,  3};
  const int k1_[11]  = { 63,128,128,128,128, 63,128,128,128, 27, 64};
  const int o1_[11]  = {  0,  0,  0,  0,  0,128,  0,  0,  0,128,  0};
  const int k2_[11]  = {999,999,999,999,999, 64,999,999,999, 64,999};
  const int do_[11]  = {0,8192,24576,40960,57344,73728,98304,114688,131072,149504,161792};

  int c = blockIdx.x;
  const float* src =
    c==0?s0: c==1?s1: c==2?s2: c==3?s3: c==4?s4: c==5?s5:
    c==6?s6: c==7?s7: c==8?s8: c==9?s9: s10;
  int nw=nw_[c], kw=kw_[c], nc=nc_[c], k1=k1_[c], o1=o1_[c], k2=k2_[c];
  int KS = kw >> 5;
  int total = nw * kw;
  for (int idx = blockIdx.y * blockDim.x + threadIdx.x; idx < total;
       idx += gridDim.y * blockDim.x) {
    int e   = idx & 7;
    int l15 = (idx >> 3) & 15;
    int lg  = (idx >> 7) & 3;
    int r   = idx >> 9;
    int ks  = r % KS;
    int nt  = r / KS;
    int n = nt * 16 + l15;
    int k = ks * 32 + lg * 8 + e;
    float v = 0.f;
    if (n < nc) {
      if (k < k1)       v = src[(o1 + k) * nc + n];
      else if (k >= k2) v = src[(k - k2) * nc + n];
    }
    dst[do_[c] + idx] = f2bf(v);
  }
}

// ---------------- posenc: 32 cols of one row, XOR-swizzled (inline, runs once) ----------------
template<int I0, int L>
__device__ __forceinline__ void posenc_store(unsigned char* actb, int row,
                                             float p0, float p1, float p2)
{
#pragma unroll
  for (int q = 0; q < 4; q++) {
    float hv[8];
#pragma unroll
    for (int e = 0; e < 8; e++) {
      const int i = I0 + q * 8 + e;
      float v;
      if (i == 0) v = p0;
      else if (i == 1) v = p1;
      else if (i == 2) v = p2;
      else {
        const int idx = i - 3, j = idx / 6, t = idx % 6;
        if (j < L) {
          const float sc = (float)(1 << j);
          const float a  = (t % 3 == 0 ? p0 : (t % 3 == 1 ? p1 : p2)) * sc;
          v = (t < 3) ? __sinf(a) : __cosf(a);
        } else v = 0.f;
      }
      hv[e] = v;
    }
    uint4 pk;
    pk.x = pk2bf(hv[0], hv[1]);
    pk.y = pk2bf(hv[2], hv[3]);
    pk.z = pk2bf(hv[4], hv[5]);
    pk.w = pk2bf(hv[6], hv[7]);
    int b = (row * ROWB + (I0 + q * 8) * 2) ^ ((row & 7) << 4);
    *(uint4*)(actb + b) = pk;
  }
}

// ---------------- weight prefetch: FIRST ks-step of next layer -> pf[2] (8 regs) ----------------
template<int KSN>
__device__ __forceinline__ void preloadW1(bf16x8* pf, const unsigned short* wchunk,
                                          int lane, int wn)
{
  if (KSN == 0) return;
  const unsigned short* wl = wchunk + (wn * 2) * (KSN * 512) + lane * 8;
#pragma unroll
  for (int nt = 0; nt < 2; nt++)
    pf[nt] = *(const bf16x8*)(wl + (nt * KSN) * 512);
}

// ---------------- 2x4 tile layer: wave (wm,wn) = rows [wm*64,+64) x ntiles [wn*2,+2) ----------------
// acc[4][2] = 32 regs/wave -> fits 4 waves/SIMD. ks=0 uses pf; prefetch next after ks loop.
template<int KS, int KSN, int KB, int DST, bool RELU, bool MIDBAR, bool SIG>
__device__ __forceinline__ void layer22(
    unsigned char* actb, const unsigned short* __restrict__ wchunk,
    const unsigned short* __restrict__ wnext, bf16x8* pf,
    const unsigned (*rb2)[2], const unsigned (*wb2)[2],
    int lane, int wid, float* __restrict__ out, long grow0)
{
  const int l15 = lane & 15;
  const int lg  = lane >> 4;
  const int wn  = wid & 3;
  const unsigned short* wl = wchunk + (wn * 2) * (KS * 512) + lane * 8;
  const f32x4 vzero = {0.f, 0.f, 0.f, 0.f};
  f32x4 acc[4][2];

  {                                    // ks = 0 peeled (weights from pf)
    bf16x8 bfr4[4];
#pragma unroll
    for (int mq = 0; mq < 4; mq++)
      bfr4[mq] = *(const bf16x8*)(actb + rb2[mq][0] + KB * 2);
#pragma unroll
    for (int nt = 0; nt < 2; nt++)
#pragma unroll
      for (int mq = 0; mq < 4; mq++)
        acc[mq][nt] = __builtin_amdgcn_mfma_f32_16x16x32_bf16(
            pf[nt], bfr4[mq], vzero, 0, 0, 0);
  }
#pragma unroll
  for (int ks = 1; ks < KS; ks++) {
    bf16x8 afr[2];
#pragma unroll
    for (int nt = 0; nt < 2; nt++)
      afr[nt] = *(const bf16x8*)(wl + (nt * KS + ks) * 512);
    bf16x8 bfr4[4];
#pragma unroll
    for (int mq = 0; mq < 4; mq++)
      bfr4[mq] = *(const bf16x8*)(actb + rb2[mq][ks & 1] + (KB * 2 + (ks >> 1) * 128));
#pragma unroll
    for (int nt = 0; nt < 2; nt++)
#pragma unroll
      for (int mq = 0; mq < 4; mq++)
        acc[mq][nt] = __builtin_amdgcn_mfma_f32_16x16x32_bf16(
            afr[nt], bfr4[mq], acc[mq][nt], 0, 0, 0);
  }

  // prefetch NEXT layer's first ks-step (issued now; waited at next layer's first MFMA)
  preloadW1<KSN>(pf, wnext, lane, wn);

  f32x4 accs;
  if (SIG) {   // sigma tile (chunk nt==8): wave wid owns m-tile wid (rows wid*16..+16)
    accs = vzero;
#pragma unroll
    for (int ks = 0; ks < KS; ks++) {
      bf16x8 afs = *(const bf16x8*)(wchunk + (8 * KS + ks) * 512 + lane * 8);
      int m = wid * 16 + l15;
      int byt = (m * ROWB + KB * 2 + ks * 64 + lg * 16) ^ ((m & 7) << 4);
      bf16x8 bfs = *(const bf16x8*)(actb + byt);
      accs = __builtin_amdgcn_mfma_f32_16x16x32_bf16(afs, bfs, accs, 0, 0, 0);
    }
  }

  if (MIDBAR) barL();              // all reads of old act done before any write

#pragma unroll
  for (int mq = 0; mq < 4; mq++) {
#pragma unroll
    for (int nt = 0; nt < 2; nt++) {
      f32x4 v = acc[mq][nt];
      if (RELU) {
        v.x = fmaxf(v.x, 0.f); v.y = fmaxf(v.y, 0.f);
        v.z = fmaxf(v.z, 0.f); v.w = fmaxf(v.w, 0.f);
      }
      uint2 pk;
      pk.x = pk2bf(v.x, v.y);
      pk.y = pk2bf(v.z, v.w);
      *(uint2*)(actb + wb2[mq][nt] + DST * 2) = pk;
    }
  }
  if (SIG && lg == 0) {
    int m = wid * 16 + l15;
    out[3L * NTOT + grow0 + m] = fmaxf(accs.x, 0.f);
  }
  barL();                          // writes visible before next layer reads
}

// ---------------- b3_w0: 8 waves = 4 ntiles x 2 row-halves, K=192, inline XOR ----------------
__device__ __forceinline__ void layer_b3w0(
    unsigned char* actb, const unsigned short* __restrict__ wchunk,
    int lane, int wid)
{
  const int l15 = lane & 15;
  const int lg  = lane >> 4;
  const int nt4 = wid & 3;          // n-tile 0..3
  const int mh  = wid >> 2;         // row half
  const unsigned short* wl = wchunk + nt4 * (6 * 512) + lane * 8;
  const f32x4 vzero = {0.f, 0.f, 0.f, 0.f};
  f32x4 acc[4];

  {                                    // ks = 0 peeled
    bf16x8 afr = *(const bf16x8*)(wl);
#pragma unroll
    for (int mt = 0; mt < 4; mt++) {
      int m = mh * 64 + mt * 16 + l15;
      int byt = (m * ROWB + lg * 16) ^ ((m & 7) << 4);
      bf16x8 b = *(const bf16x8*)(actb + byt);
      acc[mt] = __builtin_amdgcn_mfma_f32_16x16x32_bf16(afr, b, vzero, 0, 0, 0);
    }
  }
#pragma unroll
  for (int ks = 1; ks < 6; ks++) {
    bf16x8 afr = *(const bf16x8*)(wl + ks * 512);
#pragma unroll
    for (int mt = 0; mt < 4; mt++) {
      int m = mh * 64 + mt * 16 + l15;
      int byt = (m * ROWB + ks * 64 + lg * 16) ^ ((m & 7) << 4);
      bf16x8 b = *(const bf16x8*)(actb + byt);
      acc[mt] = __builtin_amdgcn_mfma_f32_16x16x32_bf16(afr, b, acc[mt], 0, 0, 0);
    }
  }

  barL();                          // reads done before writes

#pragma unroll
  for (int mt = 0; mt < 4; mt++) {
    f32x4 v = acc[mt];
    v.x = fmaxf(v.x, 0.f); v.y = fmaxf(v.y, 0.f);
    v.z = fmaxf(v.z, 0.f); v.w = fmaxf(v.w, 0.f);
    uint2 pk;
    pk.x = pk2bf(v.x, v.y);
    pk.y = pk2bf(v.z, v.w);
    int m = mh * 64 + mt * 16 + l15;
    int byt = (m * ROWB + nt4 * 32 + lg * 8) ^ ((m & 7) << 4);
    *(uint2*)(actb + byt) = pk;
  }
  barL();
}

// color: wave wid owns m-tile wid; reads c1 cols 0..63; writes global only
__device__ __forceinline__ void color_n(
    unsigned char* actb, const unsigned short* __restrict__ wchunk,
    int lane, int wid, float* __restrict__ out, long grow0)
{
  const int l15 = lane & 15;
  const int lg  = lane >> 4;
  const f32x4 vzero = {0.f, 0.f, 0.f, 0.f};
  f32x4 acc;
  int m = wid * 16 + l15;
#pragma unroll
  for (int ks = 0; ks < 2; ks++) {
    bf16x8 afr = *(const bf16x8*)(wchunk + ks * 512 + lane * 8);
    int ba = (m * ROWB + ks * 64 + lg * 16) ^ ((m & 7) << 4);
    bf16x8 b = *(const bf16x8*)(actb + ba);
    if (ks == 0) acc = __builtin_amdgcn_mfma_f32_16x16x32_bf16(afr, b, vzero, 0, 0, 0);
    else         acc = __builtin_amdgcn_mfma_f32_16x16x32_bf16(afr, b, acc, 0, 0, 0);
  }
  if (lg == 0) {
    long g3 = (grow0 + m) * 3;
    out[g3 + 0] = 1.f / (1.f + __expf(-acc.x));
    out[g3 + 1] = 1.f / (1.f + __expf(-acc.y));
    out[g3 + 2] = 1.f / (1.f + __expf(-acc.z));
  }
}

__global__ __launch_bounds__(BLK, 4) void nerf_fused(
    const float* __restrict__ pos, const float* __restrict__ dirs,
    const unsigned short* __restrict__ wp, float* __restrict__ out)
{
  __shared__ unsigned char actb[ACT_BYTES];   // act[128][192] bf16, XOR-swizzled rows

  const int tid   = threadIdx.x;
  const int lane  = tid & 63;
  const int wid   = tid >> 6;                 // 0..7
  const int wm    = wid >> 2;                 // row half
  const int wn    = wid & 3;                  // col quarter
  const long grow0 = (long)blockIdx.x * MWG;

  const int l15 = lane & 15;
  const int lg  = lane >> 4;

  // per-thread swizzled LDS bases; in-loop imms have bits>=7 only -> commute with mask
  unsigned rb2[4][2], wb2[4][2];
#pragma unroll
  for (int mq = 0; mq < 4; mq++) {
    int m = wm * 64 + mq * 16 + l15;
    unsigned sw = (unsigned)((m & 7) << 4);
    unsigned base = (unsigned)(m * ROWB);
    rb2[mq][0] = (base + lg * 16) ^ sw;
    rb2[mq][1] = (base + 64 + lg * 16) ^ sw;
#pragma unroll
    for (int nt = 0; nt < 2; nt++)
      wb2[mq][nt] = (base + (wn * 2 + nt) * 32 + lg * 8) ^ sw;
  }

  // prefetch b1_w0's first ks-step (2 frags); loads overlap the posenc trig below
  bf16x8 pf[2];
  preloadW1<2>(pf, wp + 0, lane, wn);

  // posenc(pos) -> cols 0..62 (col 63 = 0); waves 0..3 cover rows 0..127
  if (wid < 4) {
    int row = wid * 32 + (lane & 31);
    long g  = grow0 + row;
    float p0 = pos[g * 3 + 0], p1 = pos[g * 3 + 1], p2 = pos[g * 3 + 2];
    if (lane < 32) posenc_store<0, 10>(actb, row, p0, p1, p2);
    else           posenc_store<32, 10>(actb, row, p0, p1, p2);
  }
  barL();

  // b1_w0: reads cols 0..63, writes 64..191 (disjoint -> no midbar)
  layer22<2, 4, 0, 64, true, false, false>(actb, wp +      0, wp +   8192, pf, rb2, wb2, lane, wid, out, grow0);
  layer22<4, 4, 64, 64, true, true, false>(actb, wp +   8192, wp +  24576, pf, rb2, wb2, lane, wid, out, grow0); // b1_w1
  layer22<4, 4, 64, 64, true, true, false>(actb, wp +  24576, wp +  40960, pf, rb2, wb2, lane, wid, out, grow0); // b1_w2
  layer22<4, 4, 64, 64, true, true, false>(actb, wp +  40960, wp +  57344, pf, rb2, wb2, lane, wid, out, grow0); // b1_w3
  layer22<4, 6, 64, 64, true, true, false>(actb, wp +  57344, wp +  73728, pf, rb2, wb2, lane, wid, out, grow0); // b1_w4
  // b2_w0: K=192 reads 0..191, writes 64..191
  layer22<6, 4, 0, 64, true, true, false>(actb, wp +  73728, wp +  98304, pf, rb2, wb2, lane, wid, out, grow0);

  // posenc(dirs) -> cols 0..26 (27..63 zero); waves 0..3, own rows (b2_w0's midbar fenced reads)
  if (wid < 4) {
    int row = wid * 32 + (lane & 31);
    long g  = grow0 + row;
    float p0 = dirs[g * 3 + 0], p1 = dirs[g * 3 + 1], p2 = dirs[g * 3 + 2];
    if (lane < 32) posenc_store<0, 4>(actb, row, p0, p1, p2);
    else           posenc_store<32, 4>(actb, row, p0, p1, p2);   // all zeros
  }

  layer22<4, 4, 64, 64, true, true, false>(actb, wp +  98304, wp + 114688, pf, rb2, wb2, lane, wid, out, grow0); // b2_w1
  layer22<4, 4, 64, 64, true, true, false>(actb, wp + 114688, wp + 131072, pf, rb2, wb2, lane, wid, out, grow0); // b2_w2
  // b2_w3: feat (no relu) + sigma tile (SIG); no further prefetch
  layer22<4, 0, 64, 64, false, true, true>(actb, wp + 131072, nullptr,     pf, rb2, wb2, lane, wid, out, grow0);
  // b3_w0: K=192 reads 0..191 (d_emb|feat), writes c1 cols 0..63
  layer_b3w0(actb, wp + 149504, lane, wid);
  // b3_w1 -> color (global only)
  color_n(actb, wp + 161792, lane, wid, out, grow0);
}

extern "C" void kernel_launch(void* const* d_in, const int* in_sizes, int n_in,
                              void* d_out, int out_size, void* d_ws, size_t ws_size,
                              hipStream_t stream)
{
  const float* pos  = (const float*)d_in[0];
  const float* dirs = (const float*)d_in[1];
  unsigned short* wpack = (unsigned short*)d_ws;   // 325,632 B used
  float* out = (float*)d_out;

  prepack_k<<<dim3(11, 12, 1), 256, 0, stream>>>(
      (const float*)d_in[2], (const float*)d_in[3], (const float*)d_in[4],
      (const float*)d_in[5], (const float*)d_in[6], (const float*)d_in[7],
      (const float*)d_in[8], (const float*)d_in[9], (const float*)d_in[10],
      (const float*)d_in[11], (const float*)d_in[12], wpack);

  nerf_fused<<<NTOT / MWG, BLK, 0, stream>>>(pos, dirs, wpack, out);
}

// Round 24
// 325.629 us; speedup vs baseline: 1.0920x; 1.0920x over previous
//
#include <hip/hip_runtime.h>
#include <hip/hip_bf16.h>

#define NTOT  1048576
#define MWG   128          // rows per workgroup
#define BLK   256          // 4 waves in 2x2: wave (wm,wn) owns rows [wm*64,+64) x ntiles [wn*4,+4)
#define ROWB  384          // act row stride bytes; XOR swizzle (m&7)<<4, bases precomputed
#define ACT_BYTES  (MWG * ROWB)          // 49152; x3 blocks = 147 KB <= 160 KB

typedef __attribute__((ext_vector_type(8))) short  bf16x8;
typedef __attribute__((ext_vector_type(4))) float  f32x4;

// lgkm-only barrier: LDS ordering needs lgkmcnt only; no vmcnt drain -> global loads
// issued before the barrier stay in flight across it (weight prefetch relies on this)
__device__ __forceinline__ void barL() {
  asm volatile("s_waitcnt lgkmcnt(0)\n\ts_barrier" ::: "memory");
}

__device__ __forceinline__ unsigned short f2bf(float f) {
  unsigned u = __float_as_uint(f);
  u += 0x7fffu + ((u >> 16) & 1u);          // RNE
  return (unsigned short)(u >> 16);
}

__device__ __forceinline__ unsigned pk2bf(float lo, float hi) {
  float2 t; t.x = lo; t.y = hi;
  __hip_bfloat162 b = __float22bfloat162_rn(t);   // RNE
  return *(unsigned*)&b;
}

// ---------------- weight prepack (identical to R6..R22) ----------------
__global__ __launch_bounds__(256) void prepack_k(
    const float* __restrict__ s0, const float* __restrict__ s1,
    const float* __restrict__ s2, const float* __restrict__ s3,
    const float* __restrict__ s4, const float* __restrict__ s5,
    const float* __restrict__ s6, const float* __restrict__ s7,
    const float* __restrict__ s8, const float* __restrict__ s9,
    const float* __restrict__ s10, unsigned short* __restrict__ dst)
{
  const int nw_[11]  = {128,128,128,128,128,128,128,128,144, 64, 16};
  const int kw_[11]  = { 64,128,128,128,128,192,128,128,128,192, 64};
  const int nc_[11]  = {128,128,128,128,128,128,128,128,129, 64,  3};
  const int k1_[11]  = { 63,128,128,128,128, 63,128,128,128, 27, 64};
  const int o1_[11]  = {  0,  0,  0,  0,  0,128,  0,  0,  0,128,  0};
  const int k2_[11]  = {999,999,999,999,999, 64,999,999,999, 64,999};
  const int do_[11]  = {0,8192,24576,40960,57344,73728,98304,114688,131072,149504,161792};

  int c = blockIdx.x;
  const float* src =
    c==0?s0: c==1?s1: c==2?s2: c==3?s3: c==4?s4: c==5?s5:
    c==6?s6: c==7?s7: c==8?s8: c==9?s9: s10;
  int nw=nw_[c], kw=kw_[c], nc=nc_[c], k1=k1_[c], o1=o1_[c], k2=k2_[c];
  int KS = kw >> 5;
  int total = nw * kw;
  for (int idx = blockIdx.y * blockDim.x + threadIdx.x; idx < total;
       idx += gridDim.y * blockDim.x) {
    int e   = idx & 7;
    int l15 = (idx >> 3) & 15;
    int lg  = (idx >> 7) & 3;
    int r   = idx >> 9;
    int ks  = r % KS;
    int nt  = r / KS;
    int n = nt * 16 + l15;
    int k = ks * 32 + lg * 8 + e;
    float v = 0.f;
    if (n < nc) {
      if (k < k1)       v = src[(o1 + k) * nc + n];
      else if (k >= k2) v = src[(k - k2) * nc + n];
    }
    dst[do_[c] + idx] = f2bf(v);
  }
}

// ---------------- posenc: 32 cols of one row, XOR-swizzled (inline, runs once) ----------------
template<int I0, int L>
__device__ __forceinline__ void posenc_store(unsigned char* actb, int row,
                                             float p0, float p1, float p2)
{
#pragma unroll
  for (int q = 0; q < 4; q++) {
    float hv[8];
#pragma unroll
    for (int e = 0; e < 8; e++) {
      const int i = I0 + q * 8 + e;
      float v;
      if (i == 0) v = p0;
      else if (i == 1) v = p1;
      else if (i == 2) v = p2;
      else {
        const int idx = i - 3, j = idx / 6, t = idx % 6;
        if (j < L) {
          const float sc = (float)(1 << j);
          const float a  = (t % 3 == 0 ? p0 : (t % 3 == 1 ? p1 : p2)) * sc;
          v = (t < 3) ? __sinf(a) : __cosf(a);
        } else v = 0.f;
      }
      hv[e] = v;
    }
    uint4 pk;
    pk.x = pk2bf(hv[0], hv[1]);
    pk.y = pk2bf(hv[2], hv[3]);
    pk.z = pk2bf(hv[4], hv[5]);
    pk.w = pk2bf(hv[6], hv[7]);
    int b = (row * ROWB + (I0 + q * 8) * 2) ^ ((row & 7) << 4);
    *(uint4*)(actb + b) = pk;
  }
}

// ---------------- weight prefetch: FIRST ks-step only of next layer -> pf[4] (16 regs) ----------------
template<int KSN>
__device__ __forceinline__ void preloadW1(bf16x8* pf, const unsigned short* wchunk,
                                          int lane, int wn)
{
  if (KSN == 0) return;
  const unsigned short* wl = wchunk + (wn * 4) * (KSN * 512) + lane * 8;
#pragma unroll
  for (int nt = 0; nt < 4; nt++)
    pf[nt] = *(const bf16x8*)(wl + (nt * KSN) * 512);
}

// ---------------- 2x2 tile layer with 1-step cross-layer weight prefetch + setprio ----------------
// ks=0 uses pf (prefetched during the PREVIOUS layer); ks>=1 loads directly.
// MFMA clusters wrapped in s_setprio(1)/(0): favors MFMA-phase waves on the CU scheduler
// against load-phase waves of drifting sibling blocks (T5).
template<int KS, int KSN, int KB, int DST, bool RELU, bool MIDBAR, bool SIG>
__device__ __forceinline__ void layer22(
    unsigned char* actb, const unsigned short* __restrict__ wchunk,
    const unsigned short* __restrict__ wnext, bf16x8* pf,
    const unsigned (*rb2)[2], const unsigned (*wb2)[4],
    int lane, int wid, float* __restrict__ out, long grow0)
{
  const int l15 = lane & 15;
  const int lg  = lane >> 4;
  const int wn  = wid & 1;
  const unsigned short* wl = wchunk + (wn * 4) * (KS * 512) + lane * 8;
  const f32x4 vzero = {0.f, 0.f, 0.f, 0.f};
  f32x4 acc[4][4];

  {                                    // ks = 0 peeled (weights from pf)
    bf16x8 bfr4[4];
#pragma unroll
    for (int mq = 0; mq < 4; mq++)
      bfr4[mq] = *(const bf16x8*)(actb + rb2[mq][0] + KB * 2);
    __builtin_amdgcn_s_setprio(1);
#pragma unroll
    for (int nt = 0; nt < 4; nt++)
#pragma unroll
      for (int mq = 0; mq < 4; mq++)
        acc[mq][nt] = __builtin_amdgcn_mfma_f32_16x16x32_bf16(
            pf[nt], bfr4[mq], vzero, 0, 0, 0);
    __builtin_amdgcn_s_setprio(0);
  }
#pragma unroll
  for (int ks = 1; ks < KS; ks++) {
    bf16x8 afr[4];
#pragma unroll
    for (int nt = 0; nt < 4; nt++)
      afr[nt] = *(const bf16x8*)(wl + (nt * KS + ks) * 512);
    bf16x8 bfr4[4];
#pragma unroll
    for (int mq = 0; mq < 4; mq++)
      bfr4[mq] = *(const bf16x8*)(actb + rb2[mq][ks & 1] + (KB * 2 + (ks >> 1) * 128));
    __builtin_amdgcn_s_setprio(1);
#pragma unroll
    for (int nt = 0; nt < 4; nt++)
#pragma unroll
      for (int mq = 0; mq < 4; mq++)
        acc[mq][nt] = __builtin_amdgcn_mfma_f32_16x16x32_bf16(
            afr[nt], bfr4[mq], acc[mq][nt], 0, 0, 0);
    __builtin_amdgcn_s_setprio(0);
  }

  // prefetch NEXT layer's first ks-step (issued now; waited at next layer's first MFMA)
  preloadW1<KSN>(pf, wnext, lane, wn);

  f32x4 accs[2];
  if (SIG) {   // sigma tile (chunk nt==8), m-tiles {2*wid, 2*wid+1}; inline XOR addrs
    accs[0] = vzero; accs[1] = vzero;
#pragma unroll
    for (int ks = 0; ks < KS; ks++) {
      bf16x8 afs = *(const bf16x8*)(wchunk + (8 * KS + ks) * 512 + lane * 8);
#pragma unroll
      for (int j = 0; j < 2; j++) {
        int m = (2 * wid + j) * 16 + l15;
        int byt = (m * ROWB + KB * 2 + ks * 64 + lg * 16) ^ ((m & 7) << 4);
        bf16x8 bfs = *(const bf16x8*)(actb + byt);
        accs[j] = __builtin_amdgcn_mfma_f32_16x16x32_bf16(afs, bfs, accs[j], 0, 0, 0);
      }
    }
  }

  if (MIDBAR) barL();              // all reads of old act done before any write

#pragma unroll
  for (int mq = 0; mq < 4; mq++) {
#pragma unroll
    for (int nt = 0; nt < 4; nt++) {
      f32x4 v = acc[mq][nt];
      if (RELU) {
        v.x = fmaxf(v.x, 0.f); v.y = fmaxf(v.y, 0.f);
        v.z = fmaxf(v.z, 0.f); v.w = fmaxf(v.w, 0.f);
      }
      uint2 pk;
      pk.x = pk2bf(v.x, v.y);
      pk.y = pk2bf(v.z, v.w);
      *(uint2*)(actb + wb2[mq][nt] + DST * 2) = pk;
    }
  }
  if (SIG && lg == 0) {
#pragma unroll
    for (int j = 0; j < 2; j++) {
      int m = (2 * wid + j) * 16 + l15;
      out[3L * NTOT + grow0 + m] = fmaxf(accs[j].x, 0.f);
    }
  }
  barL();                          // writes visible before next layer reads
}

// ---------------- b3_w0: full-row N-split (64 outputs, 1 ntile/wave), K=192, inline XOR ----------------
__device__ __forceinline__ void layer_b3w0(
    unsigned char* actb, const unsigned short* __restrict__ wchunk,
    int lane, int wid)
{
  const int l15 = lane & 15;
  const int lg  = lane >> 4;
  const unsigned short* wl = wchunk + wid * (6 * 512) + lane * 8;
  const f32x4 vzero = {0.f, 0.f, 0.f, 0.f};
  f32x4 acc[8];

  {                                    // ks = 0 peeled
    bf16x8 afr = *(const bf16x8*)(wl);
#pragma unroll
    for (int mt = 0; mt < 8; mt++) {
      int m = mt * 16 + l15;
      int byt = (m * ROWB + lg * 16) ^ ((m & 7) << 4);
      bf16x8 b = *(const bf16x8*)(actb + byt);
      acc[mt] = __builtin_amdgcn_mfma_f32_16x16x32_bf16(afr, b, vzero, 0, 0, 0);
    }
  }
#pragma unroll
  for (int ks = 1; ks < 6; ks++) {
    bf16x8 afr = *(const bf16x8*)(wl + ks * 512);
#pragma unroll
    for (int mt = 0; mt < 8; mt++) {
      int m = mt * 16 + l15;
      int byt = (m * ROWB + ks * 64 + lg * 16) ^ ((m & 7) << 4);
      bf16x8 b = *(const bf16x8*)(actb + byt);
      acc[mt] = __builtin_amdgcn_mfma_f32_16x16x32_bf16(afr, b, acc[mt], 0, 0, 0);
    }
  }

  barL();                          // reads done before writes

#pragma unroll
  for (int mt = 0; mt < 8; mt++) {
    f32x4 v = acc[mt];
    v.x = fmaxf(v.x, 0.f); v.y = fmaxf(v.y, 0.f);
    v.z = fmaxf(v.z, 0.f); v.w = fmaxf(v.w, 0.f);
    uint2 pk;
    pk.x = pk2bf(v.x, v.y);
    pk.y = pk2bf(v.z, v.w);
    int m = mt * 16 + l15;
    int byt = (m * ROWB + wid * 32 + lg * 8) ^ ((m & 7) << 4);
    *(uint2*)(actb + byt) = pk;
  }
  barL();
}

// color: single n-tile, m-split {2*wid, 2*wid+1}; inline XOR; writes global only
__device__ __forceinline__ void color_n(
    unsigned char* actb, const unsigned short* __restrict__ wchunk,
    int lane, int wid, float* __restrict__ out, long grow0)
{
  const int l15 = lane & 15;
  const int lg  = lane >> 4;
  const f32x4 vzero = {0.f, 0.f, 0.f, 0.f};
  f32x4 acc[2];
  int m0 = (2 * wid + 0) * 16 + l15;
  int m1 = (2 * wid + 1) * 16 + l15;
#pragma unroll
  for (int ks = 0; ks < 2; ks++) {
    bf16x8 afr = *(const bf16x8*)(wchunk + ks * 512 + lane * 8);
    int b0a = (m0 * ROWB + ks * 64 + lg * 16) ^ ((m0 & 7) << 4);
    int b1a = (m1 * ROWB + ks * 64 + lg * 16) ^ ((m1 & 7) << 4);
    bf16x8 b0 = *(const bf16x8*)(actb + b0a);
    bf16x8 b1 = *(const bf16x8*)(actb + b1a);
    if (ks == 0) {
      acc[0] = __builtin_amdgcn_mfma_f32_16x16x32_bf16(afr, b0, vzero, 0, 0, 0);
      acc[1] = __builtin_amdgcn_mfma_f32_16x16x32_bf16(afr, b1, vzero, 0, 0, 0);
    } else {
      acc[0] = __builtin_amdgcn_mfma_f32_16x16x32_bf16(afr, b0, acc[0], 0, 0, 0);
      acc[1] = __builtin_amdgcn_mfma_f32_16x16x32_bf16(afr, b1, acc[1], 0, 0, 0);
    }
  }
  if (lg == 0) {
#pragma unroll
    for (int j = 0; j < 2; j++) {
      int m = (2 * wid + j) * 16 + l15;
      long g3 = (grow0 + m) * 3;
      out[g3 + 0] = 1.f / (1.f + __expf(-acc[j].x));
      out[g3 + 1] = 1.f / (1.f + __expf(-acc[j].y));
      out[g3 + 2] = 1.f / (1.f + __expf(-acc[j].z));
    }
  }
}

__global__ __launch_bounds__(BLK, 2) void nerf_fused(
    const float* __restrict__ pos, const float* __restrict__ dirs,
    const unsigned short* __restrict__ wp, float* __restrict__ out)
{
  __shared__ unsigned char actb[ACT_BYTES];   // act[128][192] bf16, XOR-swizzled rows

  const int tid   = threadIdx.x;
  const int lane  = tid & 63;
  const int wid   = tid >> 6;
  const int wm    = wid >> 1;                 // row half
  const int wn    = wid & 1;                  // col half
  const long grow0 = (long)blockIdx.x * MWG;

  const int l15 = lane & 15;
  const int lg  = lane >> 4;

  // per-thread swizzled LDS bases; in-loop imms have bits>=7 only -> commute with mask
  unsigned rb2[4][2], wb2[4][4];
#pragma unroll
  for (int mq = 0; mq < 4; mq++) {
    int m = wm * 64 + mq * 16 + l15;
    unsigned sw = (unsigned)((m & 7) << 4);
    unsigned base = (unsigned)(m * ROWB);
    rb2[mq][0] = (base + lg * 16) ^ sw;
    rb2[mq][1] = (base + 64 + lg * 16) ^ sw;
#pragma unroll
    for (int nt = 0; nt < 4; nt++)
      wb2[mq][nt] = (base + wn * 128 + nt * 32 + lg * 8) ^ sw;
  }

  const int row = wid * 32 + (lane & 31);
  const long g  = grow0 + row;

  // prefetch b1_w0's first ks-step (4 frags, 16 regs); loads overlap the posenc trig
  bf16x8 pf[4];
  preloadW1<2>(pf, wp + 0, lane, wn);

  // posenc(pos) -> cols 0..62 (col 63 = 0), own rows
  {
    float p0 = pos[g * 3 + 0], p1 = pos[g * 3 + 1], p2 = pos[g * 3 + 2];
    if (lane < 32) posenc_store<0, 10>(actb, row, p0, p1, p2);
    else           posenc_store<32, 10>(actb, row, p0, p1, p2);
  }
  barL();

  // b1_w0: reads cols 0..63, writes 64..191 (disjoint -> no midbar)
  layer22<2, 4, 0, 64, true, false, false>(actb, wp +      0, wp +   8192, pf, rb2, wb2, lane, wid, out, grow0);
  layer22<4, 4, 64, 64, true, true, false>(actb, wp +   8192, wp +  24576, pf, rb2, wb2, lane, wid, out, grow0); // b1_w1
  layer22<4, 4, 64, 64, true, true, false>(actb, wp +  24576, wp +  40960, pf, rb2, wb2, lane, wid, out, grow0); // b1_w2
  layer22<4, 4, 64, 64, true, true, false>(actb, wp +  40960, wp +  57344, pf, rb2, wb2, lane, wid, out, grow0); // b1_w3
  layer22<4, 6, 64, 64, true, true, false>(actb, wp +  57344, wp +  73728, pf, rb2, wb2, lane, wid, out, grow0); // b1_w4
  // b2_w0: K=192 reads 0..191, writes 64..191
  layer22<6, 4, 0, 64, true, true, false>(actb, wp +  73728, wp +  98304, pf, rb2, wb2, lane, wid, out, grow0);

  // posenc(dirs) -> cols 0..26 (27..63 zero), own rows; consumed only by b3_w0 (after barriers)
  {
    float p0 = dirs[g * 3 + 0], p1 = dirs[g * 3 + 1], p2 = dirs[g * 3 + 2];
    if (lane < 32) posenc_store<0, 4>(actb, row, p0, p1, p2);
    else           posenc_store<32, 4>(actb, row, p0, p1, p2);   // all zeros
  }

  layer22<4, 4, 64, 64, true, true, false>(actb, wp +  98304, wp + 114688, pf, rb2, wb2, lane, wid, out, grow0); // b2_w1
  layer22<4, 4, 64, 64, true, true, false>(actb, wp + 114688, wp + 131072, pf, rb2, wb2, lane, wid, out, grow0); // b2_w2
  // b2_w3: feat (no relu) + sigma tile (SIG); no further prefetch
  layer22<4, 0, 64, 64, false, true, true>(actb, wp + 131072, nullptr,     pf, rb2, wb2, lane, wid, out, grow0);
  // b3_w0: K=192 reads 0..191 (d_emb|feat), writes c1 cols 0..63
  layer_b3w0(actb, wp + 149504, lane, wid);
  // b3_w1 -> color (global only)
  color_n(actb, wp + 161792, lane, wid, out, grow0);
}

extern "C" void kernel_launch(void* const* d_in, const int* in_sizes, int n_in,
                              void* d_out, int out_size, void* d_ws, size_t ws_size,
                              hipStream_t stream)
{
  const float* pos  = (const float*)d_in[0];
  const float* dirs = (const float*)d_in[1];
  unsigned short* wpack = (unsigned short*)d_ws;   // 325,632 B used
  float* out = (float*)d_out;

  prepack_k<<<dim3(11, 12, 1), 256, 0, stream>>>(
      (const float*)d_in[2], (const float*)d_in[3], (const float*)d_in[4],
      (const float*)d_in[5], (const float*)d_in[6], (const float*)d_in[7],
      (const float*)d_in[8], (const float*)d_in[9], (const float*)d_in[10],
      (const float*)d_in[11], (const float*)d_in[12], wpack);

  nerf_fused<<<NTOT / MWG, BLK, 0, stream>>>(pos, dirs, wpack, out);
}